// Round 2
// baseline (110.147 us; speedup 1.0000x reference)
//
#include <hip/hip_runtime.h>

#define NM 64
#define NC 10
#define TWO_N 128

// out[b,c] = sum_m x[b,m] * M[m,c] + c0[c]
//   M[m,c]  = sum_k S[2k, 2m] * W[c,k]         (64x10, folded from S,W)
//   c0[c]   = b[c] + sum_k (d[2k]+bias[k]) * W[c,k]
// M/c0 are recomputed redundantly per block (S is 64 KB -> L2-resident; the
// 160 extra FMAs/thread are noise vs. the 51 MB x stream). This removes the
// previous single-block precompute kernel (1 CU, latency-bound strided HBM
// reads) and its same-stream serialization bubble.

__global__ __launch_bounds__(256) void cv2d_fused(
    const float* __restrict__ x,     // [B, 64]
    const float* __restrict__ S,     // [128, 128]
    const float* __restrict__ dvec,  // [128]
    const float* __restrict__ bias,  // [64]
    const float* __restrict__ W,     // [10, 64]
    const float* __restrict__ bvec,  // [10]
    float* __restrict__ out,         // [B, 10]
    int Bn)
{
    // Row stride 64 floats = 256 B: &Ms[c][4q] is always 16 B-aligned -> ds_read_b128.
    __shared__ __align__(16) float Ms[NC][NM];
    __shared__ float c0s[NC];
    const int t = threadIdx.x;

    // Phase 1: fold S,W -> M (640 entries, ~2.5 per thread).
    for (int e = t; e < NM * NC; e += 256) {
        const int c = e >> 6;   // e / 64
        const int m = e & 63;   // e % 64
        float acc = 0.f;
        #pragma unroll
        for (int k = 0; k < NM; ++k)
            acc += S[(2 * k) * TWO_N + 2 * m] * W[c * NM + k];
        Ms[c][m] = acc;
    }
    if (t < NC) {
        float acc = bvec[t];
        #pragma unroll
        for (int k = 0; k < NM; ++k)
            acc += (dvec[2 * k] + bias[k]) * W[t * NM + k];
        c0s[t] = acc;
    }
    __syncthreads();

    // Phase 2: one row per thread, streamed from HBM at float4 width.
    const int row = blockIdx.x * 256 + t;
    if (row >= Bn) return;

    const float4* __restrict__ xr = (const float4*)(x + (size_t)row * NM);

    float acc[NC];
    #pragma unroll
    for (int c = 0; c < NC; ++c) acc[c] = c0s[c];

    #pragma unroll
    for (int q = 0; q < NM / 4; ++q) {
        const float4 v = xr[q];
        #pragma unroll
        for (int c = 0; c < NC; ++c) {
            // Wave-uniform address -> LDS broadcast read, conflict-free.
            const float4 mm = *(const float4*)&Ms[c][4 * q];
            acc[c] += v.x * mm.x;
            acc[c] += v.y * mm.y;
            acc[c] += v.z * mm.z;
            acc[c] += v.w * mm.w;
        }
    }

    // 10 floats = 40 B per row: 8 B-aligned -> float2 stores.
    float2* __restrict__ o = (float2*)(out + (size_t)row * NC);
    #pragma unroll
    for (int c = 0; c < NC; c += 2)
        o[c / 2] = make_float2(acc[c], acc[c + 1]);
}

extern "C" void kernel_launch(void* const* d_in, const int* in_sizes, int n_in,
                              void* d_out, int out_size, void* d_ws, size_t ws_size,
                              hipStream_t stream) {
    const float* x    = (const float*)d_in[0];
    const float* S    = (const float*)d_in[1];
    const float* d    = (const float*)d_in[2];
    const float* bias = (const float*)d_in[3];
    const float* W    = (const float*)d_in[4];
    const float* bvec = (const float*)d_in[5];
    float* out = (float*)d_out;

    const int Bn = in_sizes[0] / NM;  // 200000

    const int grid = (Bn + 255) / 256;
    cv2d_fused<<<grid, 256, 0, stream>>>(x, S, d, bias, W, bvec, out, Bn);
}

// Round 3
// 108.377 us; speedup vs baseline: 1.0163x; 1.0163x over previous
//
#include <hip/hip_runtime.h>

#define NM 64
#define NC 10
#define TWO_N 128
#define BT 192          // block threads = rows per tile (3 waves)
#define RS 67           // LDS row stride in words: odd => bank (3t+q)%32, 2-way = free

// out[b,c] = sum_m x[b,m] * M[m,c] + c0[c]
//   M[m,c] = sum_k S[2k,2m] * W[c,k]   (64x10)
//   c0[c]  = b[c] + sum_k (d[2k]+bias[k]) * W[c,k]
// ws layout: [0..640) = M as [c][m] (row c contiguous), [640..650) = c0.

__global__ __launch_bounds__(64) void cv2d_pre(
    const float* __restrict__ S, const float* __restrict__ dvec,
    const float* __restrict__ bias, const float* __restrict__ W,
    const float* __restrict__ bvec, float* __restrict__ MC)
{
    const int c = blockIdx.x, m = threadIdx.x;
    if (c < NC) {
        float acc = 0.f;
        #pragma unroll
        for (int k = 0; k < NM; ++k)
            acc += S[(2 * k) * TWO_N + 2 * m] * W[c * NM + k];
        MC[c * NM + m] = acc;               // [c][m]
    } else if (m < NC) {                    // block 10: the constant vector
        float acc = bvec[m];
        #pragma unroll
        for (int k = 0; k < NM; ++k)
            acc += (dvec[2 * k] + bias[k]) * W[m * NM + k];
        MC[NC * NM + m] = acc;
    }
}

__global__ __launch_bounds__(BT) void cv2d_main(
    const float* __restrict__ x,    // [B,64]
    const float* __restrict__ MC,   // ws: M[10][64] + c0[10]
    float* __restrict__ out,        // [B,10]
    int Bn)
{
    __shared__ float xs[BT * RS];                   // 50.3 KB, padded tile
    __shared__ __align__(16) float Ms[NC][NM];      // 2.5 KB
    __shared__ float c0s[NC];
    const int t = threadIdx.x;

    // Stage M/c0 from ws (tiny, coalesced).
    for (int e = t; e < NC * NM; e += BT) ((float*)Ms)[e] = MC[e];
    if (t < NC) c0s[t] = MC[NC * NM + t];

    // Coalesced tile load: 192 rows x 64 floats = 3072 float4; thread t takes
    // float4 index t + 192*i -> lane addresses fully contiguous per instruction.
    const long long f0 = (long long)blockIdx.x * (BT * 16) + t;
    const long long fmax = (long long)Bn * 16;
    const float4* __restrict__ xg = (const float4*)x;
    float4 v[16];
    #pragma unroll
    for (int i = 0; i < 16; ++i) {
        const long long f = f0 + BT * i;
        v[i] = (f < fmax) ? xg[f] : make_float4(0.f, 0.f, 0.f, 0.f);
    }
    // Scatter into padded LDS: float4 #(t+192i) = elements m0..m0+3 of tile row
    // r = (t>>4) + 12*i, m0 = 4*(t&15). Odd stride RS => 2-way banks (free).
    const int r0 = t >> 4;
    const int m0 = (t & 15) * 4;
    #pragma unroll
    for (int i = 0; i < 16; ++i) {
        float* p = &xs[(r0 + 12 * i) * RS + m0];
        p[0] = v[i].x; p[1] = v[i].y; p[2] = v[i].z; p[3] = v[i].w;
    }
    __syncthreads();

    // One row per thread, read from LDS (conflict-free), 640 FMAs.
    const int row = blockIdx.x * BT + t;
    if (row >= Bn) return;

    float acc[NC];
    #pragma unroll
    for (int c = 0; c < NC; ++c) acc[c] = c0s[c];

    const float* __restrict__ xrow = &xs[t * RS];
    #pragma unroll
    for (int q = 0; q < NM / 4; ++q) {
        const float a0 = xrow[4 * q + 0];
        const float a1 = xrow[4 * q + 1];
        const float a2 = xrow[4 * q + 2];
        const float a3 = xrow[4 * q + 3];
        #pragma unroll
        for (int c = 0; c < NC; ++c) {
            const float4 mm = *(const float4*)&Ms[c][4 * q];  // wave-uniform -> broadcast
            acc[c] += a0 * mm.x + a1 * mm.y + a2 * mm.z + a3 * mm.w;
        }
    }

    float2* __restrict__ o = (float2*)(out + (size_t)row * NC);
    #pragma unroll
    for (int c = 0; c < NC; c += 2)
        o[c / 2] = make_float2(acc[c], acc[c + 1]);
}

extern "C" void kernel_launch(void* const* d_in, const int* in_sizes, int n_in,
                              void* d_out, int out_size, void* d_ws, size_t ws_size,
                              hipStream_t stream) {
    const float* x    = (const float*)d_in[0];
    const float* S    = (const float*)d_in[1];
    const float* d    = (const float*)d_in[2];
    const float* bias = (const float*)d_in[3];
    const float* W    = (const float*)d_in[4];
    const float* bvec = (const float*)d_in[5];
    float* out = (float*)d_out;
    float* MC  = (float*)d_ws;

    const int Bn = in_sizes[0] / NM;  // 200000

    cv2d_pre<<<NC + 1, 64, 0, stream>>>(S, d, bias, W, bvec, MC);

    const int grid = (Bn + BT - 1) / BT;
    cv2d_main<<<grid, BT, 0, stream>>>(x, MC, out, Bn);
}